// Round 3
// baseline (296.856 us; speedup 1.0000x reference)
//
#include <hip/hip_runtime.h>

#define BLOCK 256
#define GRID_FAST 8192
#define VPT   4    // float4 vectors per thread (fast path): 8192*256*4*4 = 2^25

typedef float vfloat4 __attribute__((ext_vector_type(4)));

__device__ __forceinline__ void kl_acc(float p, float q, float& acc) {
    // log2-space accumulation: acc += p*(log2 p - log2 q) + (1-p)*(log2(1-p) - log2(1-q))
    float omp = 1.0f - p;
    float omq = 1.0f - q;
    float d1  = __log2f(p)   - __log2f(q);
    float d2  = __log2f(omp) - __log2f(omq);
    acc = fmaf(p,   d1, acc);
    acc = fmaf(omp, d2, acc);
}

__device__ __forceinline__ void kl_acc4(vfloat4 pv, vfloat4 qv,
                                        float& a0, float& a1, float& a2, float& a3) {
    kl_acc(pv.x, qv.x, a0);
    kl_acc(pv.y, qv.y, a1);
    kl_acc(pv.z, qv.z, a2);
    kl_acc(pv.w, qv.w, a3);
}

__device__ __forceinline__ void block_reduce_and_atomic(float acc, float* out) {
    const float LN2 = 0.69314718055994530942f;
    #pragma unroll
    for (int off = 32; off > 0; off >>= 1)
        acc += __shfl_down(acc, off, 64);

    __shared__ float wave_sums[BLOCK / 64];
    const int lane = threadIdx.x & 63;
    const int wave = threadIdx.x >> 6;
    if (lane == 0) wave_sums[wave] = acc;
    __syncthreads();

    if (threadIdx.x == 0) {
        float s = 0.0f;
        #pragma unroll
        for (int w = 0; w < BLOCK / 64; ++w) s += wave_sums[w];
        atomicAdd(out, s * LN2);
    }
}

// Fast path: block-contiguous chunks, all 8 loads in flight as named registers.
__global__ __launch_bounds__(BLOCK, 8) void kl_div_fast(
        const vfloat4* __restrict__ p4,
        const vfloat4* __restrict__ q4,
        float* __restrict__ out) {
    // Block b owns float4s [b*BLOCK*VPT, (b+1)*BLOCK*VPT): contiguous 16 KB per array.
    const int base = blockIdx.x * (BLOCK * VPT) + threadIdx.x;

    // Issue all 8 loads before any use — named registers so the compiler
    // cannot collapse them into a 2-buffer pipeline.
    vfloat4 p0 = p4[base + 0 * BLOCK];
    vfloat4 p1 = p4[base + 1 * BLOCK];
    vfloat4 p2 = p4[base + 2 * BLOCK];
    vfloat4 p3 = p4[base + 3 * BLOCK];
    vfloat4 q0 = q4[base + 0 * BLOCK];
    vfloat4 q1 = q4[base + 1 * BLOCK];
    vfloat4 q2 = q4[base + 2 * BLOCK];
    vfloat4 q3 = q4[base + 3 * BLOCK];

    float a0 = 0.0f, a1 = 0.0f, a2 = 0.0f, a3 = 0.0f;
    kl_acc4(p0, q0, a0, a1, a2, a3);
    kl_acc4(p1, q1, a0, a1, a2, a3);
    kl_acc4(p2, q2, a0, a1, a2, a3);
    kl_acc4(p3, q3, a0, a1, a2, a3);

    float acc = (a0 + a1) + (a2 + a3);
    block_reduce_and_atomic(acc, out);
}

// Generic fallback: grid-stride, any N.
__global__ __launch_bounds__(BLOCK) void kl_div_generic(
        const float* __restrict__ p,
        const float* __restrict__ q,
        float* __restrict__ out,
        int n) {
    const int nvec = n >> 2;
    const vfloat4* __restrict__ p4 = reinterpret_cast<const vfloat4*>(p);
    const vfloat4* __restrict__ q4 = reinterpret_cast<const vfloat4*>(q);

    float acc = 0.0f;
    const int stride = gridDim.x * blockDim.x;
    for (int i = blockIdx.x * blockDim.x + threadIdx.x; i < nvec; i += stride) {
        vfloat4 pv = p4[i];
        vfloat4 qv = q4[i];
        kl_acc(pv.x, qv.x, acc);
        kl_acc(pv.y, qv.y, acc);
        kl_acc(pv.z, qv.z, acc);
        kl_acc(pv.w, qv.w, acc);
    }
    for (int i = (nvec << 2) + blockIdx.x * blockDim.x + threadIdx.x; i < n; i += stride) {
        kl_acc(p[i], q[i], acc);
    }
    block_reduce_and_atomic(acc, out);
}

extern "C" void kernel_launch(void* const* d_in, const int* in_sizes, int n_in,
                              void* d_out, int out_size, void* d_ws, size_t ws_size,
                              hipStream_t stream) {
    const float* p = (const float*)d_in[0];
    const float* q = (const float*)d_in[1];
    float* out = (float*)d_out;
    const int n = in_sizes[0];

    // d_out is re-poisoned to 0xAA before every timed launch — zero it.
    hipMemsetAsync(out, 0, sizeof(float), stream);

    if (n == GRID_FAST * BLOCK * VPT * 4) {
        kl_div_fast<<<GRID_FAST, BLOCK, 0, stream>>>(
            reinterpret_cast<const vfloat4*>(p),
            reinterpret_cast<const vfloat4*>(q), out);
    } else {
        kl_div_generic<<<2048, BLOCK, 0, stream>>>(p, q, out, n);
    }
}

// Round 4
// 277.677 us; speedup vs baseline: 1.0691x; 1.0691x over previous
//
#include <hip/hip_runtime.h>

#define BLOCK 256
#define GRID  2048
#define VPT   16   // float4 per thread: 2048*256*16*4 = 2^25 elements
#define BATCH 4    // float4-pairs per pipelined batch (8 loads in flight)

typedef float vfloat4 __attribute__((ext_vector_type(4)));

__device__ __forceinline__ void kl_acc(float p, float q, float& acc) {
    // log2-space: acc += p*(log2 p - log2 q) + (1-p)*(log2(1-p) - log2(1-q))
    float omp = 1.0f - p;
    float omq = 1.0f - q;
    float d1  = __log2f(p)   - __log2f(q);
    float d2  = __log2f(omp) - __log2f(omq);
    acc = fmaf(p,   d1, acc);
    acc = fmaf(omp, d2, acc);
}

__device__ __forceinline__ void kl_acc4(vfloat4 pv, vfloat4 qv,
                                        float& a0, float& a1, float& a2, float& a3) {
    kl_acc(pv.x, qv.x, a0);
    kl_acc(pv.y, qv.y, a1);
    kl_acc(pv.z, qv.z, a2);
    kl_acc(pv.w, qv.w, a3);
}

__device__ __forceinline__ void block_reduce_and_atomic(float acc, float* out) {
    const float LN2 = 0.69314718055994530942f;
    #pragma unroll
    for (int off = 32; off > 0; off >>= 1)
        acc += __shfl_down(acc, off, 64);

    __shared__ float wave_sums[BLOCK / 64];
    const int lane = threadIdx.x & 63;
    const int wave = threadIdx.x >> 6;
    if (lane == 0) wave_sums[wave] = acc;
    __syncthreads();

    if (threadIdx.x == 0) {
        float s = 0.0f;
        #pragma unroll
        for (int w = 0; w < BLOCK / 64; ++w) s += wave_sums[w];
        atomicAdd(out, s * LN2);
    }
}

// Fast path: software-pipelined batches; sched_barrier(0) pins 8 loads in
// flight behind each compute batch (compiler otherwise sinks loads to uses,
// collapsing MLP to 2 — observed VGPR_Count=28 in R2/R3).
__global__ __launch_bounds__(BLOCK, 4) void kl_div_fast(
        const vfloat4* __restrict__ p4,
        const vfloat4* __restrict__ q4,
        float* __restrict__ out) {
    const int gid = blockIdx.x * BLOCK + threadIdx.x;
    const int stride = GRID * BLOCK;

    vfloat4 pc[BATCH], qc[BATCH];
    #pragma unroll
    for (int k = 0; k < BATCH; ++k) {
        pc[k] = p4[gid + k * stride];
        qc[k] = q4[gid + k * stride];
    }

    float a0 = 0.0f, a1 = 0.0f, a2 = 0.0f, a3 = 0.0f;

    #pragma unroll
    for (int b = 1; b < VPT / BATCH; ++b) {
        vfloat4 pn[BATCH], qn[BATCH];
        #pragma unroll
        for (int k = 0; k < BATCH; ++k) {
            pn[k] = p4[gid + (b * BATCH + k) * stride];
            qn[k] = q4[gid + (b * BATCH + k) * stride];
        }
        // Nothing may move across this point: the 8 loads above are issued
        // before the 8 below-the-line compute uses of the PREVIOUS batch.
        __builtin_amdgcn_sched_barrier(0);
        #pragma unroll
        for (int k = 0; k < BATCH; ++k)
            kl_acc4(pc[k], qc[k], a0, a1, a2, a3);
        #pragma unroll
        for (int k = 0; k < BATCH; ++k) { pc[k] = pn[k]; qc[k] = qn[k]; }
    }
    __builtin_amdgcn_sched_barrier(0);
    #pragma unroll
    for (int k = 0; k < BATCH; ++k)
        kl_acc4(pc[k], qc[k], a0, a1, a2, a3);

    float acc = (a0 + a1) + (a2 + a3);
    block_reduce_and_atomic(acc, out);
}

// Generic fallback: grid-stride, any N.
__global__ __launch_bounds__(BLOCK) void kl_div_generic(
        const float* __restrict__ p,
        const float* __restrict__ q,
        float* __restrict__ out,
        int n) {
    const int nvec = n >> 2;
    const vfloat4* __restrict__ p4 = reinterpret_cast<const vfloat4*>(p);
    const vfloat4* __restrict__ q4 = reinterpret_cast<const vfloat4*>(q);

    float acc = 0.0f;
    const int stride = gridDim.x * blockDim.x;
    for (int i = blockIdx.x * blockDim.x + threadIdx.x; i < nvec; i += stride) {
        vfloat4 pv = p4[i];
        vfloat4 qv = q4[i];
        kl_acc(pv.x, qv.x, acc);
        kl_acc(pv.y, qv.y, acc);
        kl_acc(pv.z, qv.z, acc);
        kl_acc(pv.w, qv.w, acc);
    }
    for (int i = (nvec << 2) + blockIdx.x * blockDim.x + threadIdx.x; i < n; i += stride) {
        kl_acc(p[i], q[i], acc);
    }
    block_reduce_and_atomic(acc, out);
}

extern "C" void kernel_launch(void* const* d_in, const int* in_sizes, int n_in,
                              void* d_out, int out_size, void* d_ws, size_t ws_size,
                              hipStream_t stream) {
    const float* p = (const float*)d_in[0];
    const float* q = (const float*)d_in[1];
    float* out = (float*)d_out;
    const int n = in_sizes[0];

    // d_out is re-poisoned to 0xAA before every timed launch — zero it.
    hipMemsetAsync(out, 0, sizeof(float), stream);

    if (n == GRID * BLOCK * VPT * 4) {
        kl_div_fast<<<GRID, BLOCK, 0, stream>>>(
            reinterpret_cast<const vfloat4*>(p),
            reinterpret_cast<const vfloat4*>(q), out);
    } else {
        kl_div_generic<<<GRID, BLOCK, 0, stream>>>(p, q, out, n);
    }
}